// Round 3
// baseline (666.697 us; speedup 1.0000x reference)
//
#include <hip/hip_runtime.h>
#include <hip/hip_bf16.h>
#include <stdint.h>

// Problem: B=32, T=2048, D=1024, U=1024, all fp32 in/out.
// out = [context 32*1024, attention_weights 32*2048]
//
// ws layout (big mode, needs WS_NEED bytes):
//   [0, 2MB)            W1f bf16 — W1 packed in MFMA B-fragment order
//   [2MB, +128KB)       qp2 fp32 [B][U] = query@W2 + b2 + b1
//   [+128KB, +256KB)    escore fp32 [B][T] = exp(score) (unnormalized)
//   [+256KB, +4MB)      pctx fp32 [1024 blocks][1024] partial contexts
//   [+4MB, +4KB)        pden fp32 [1024] partial softmax denominators
//
// small-ws fallback (fits the previously-verified 2.49MB footprint):
//   escore -> out attw region (in-place normalize later)
//   pctx   -> atomicAdd directly into out ctx (zeroed by k_prep)
//   pden   -> 32 floats at WS_ESC (atomicAdd, zeroed by k_prep)
#define WS_W1F   0
#define WS_QP2   2097152
#define WS_ESC   (WS_QP2 + 131072)
#define WS_PCTX  (WS_ESC + 262144)
#define WS_PDEN  (WS_PCTX + 4194304)
#define WS_NEED  (WS_PDEN + 4096)

typedef __attribute__((ext_vector_type(8))) short bf16x8;
typedef __attribute__((ext_vector_type(4))) float f32x4;

__device__ inline uint16_t f2b(float f) {
    __hip_bfloat16 h = __float2bfloat16(f);
    return *reinterpret_cast<uint16_t*>(&h);
}

// async global->LDS DMA, 16B per lane; LDS dest = wave-uniform base + lane*16,
// global src = per-lane address.
__device__ inline void gl_lds16(const void* g, void* l) {
    __builtin_amdgcn_global_load_lds(
        (const __attribute__((address_space(1))) uint32_t*)g,
        (__attribute__((address_space(3))) uint32_t*)l, 16, 0, 0);
}

// ---------------- Kernel 1: prep = W1 repack + qp2 (+ optional zeroing) -----
// blocks 0..255: repack 8 fragments each (2048 fragments of 1KB total)
// blocks 256..767: qp2 on (b, u-slice of 64): 512 blocks, 256 KB of W2 each.
__global__ __launch_bounds__(256) void k_prep(const float* __restrict__ W1,
                                              const float* __restrict__ query,
                                              const float* __restrict__ W2,
                                              const float* __restrict__ b1,
                                              const float* __restrict__ b2,
                                              __hip_bfloat16* __restrict__ W1f,
                                              float* __restrict__ qp2,
                                              float* __restrict__ zctx,
                                              float* __restrict__ zden) {
    __shared__ float qs[1024];
    __shared__ float part[4][64];
    int blk = blockIdx.x, tid = threadIdx.x;
    if (blk < 256) {
        int lane = tid & 63, fi = tid >> 6;
        int l15 = lane & 15, quad = lane >> 4;
        #pragma unroll
        for (int p = 0; p < 2; ++p) {
            int frag = blk * 8 + p * 4 + fi;      // 0..2047
            int ut = frag >> 5, ks = frag & 31;
            union { uint16_t h[8]; int4 v; } pk;
            #pragma unroll
            for (int j = 0; j < 8; ++j) {
                float x = W1[(size_t)(ks * 32 + quad * 8 + j) * 1024 + ut * 16 + l15];
                pk.h[j] = f2b(x);
            }
            *(int4*)((char*)W1f + (size_t)frag * 1024 + lane * 16) = pk.v;
        }
    } else {
        int bq = blk - 256;            // 0..511
        int b = bq >> 4, us = bq & 15, u0 = us * 64;
        if (zctx != nullptr && us == 0) {
            *(float4*)(zctx + b * 1024 + tid * 4) = make_float4(0.f, 0.f, 0.f, 0.f);
            if (b == 0 && tid < 32) zden[tid] = 0.f;
        }
        const float* q = query + b * 1024;
        #pragma unroll
        for (int i = 0; i < 4; ++i) qs[i * 256 + tid] = q[i * 256 + tid];
        __syncthreads();
        int ul = tid & 63, g = tid >> 6;       // 4 d-groups x 64 u
        float a = 0.f;
        const float* w2p = W2 + (size_t)(g * 256) * 1024 + u0 + ul;
        const float* qg = qs + g * 256;
        #pragma unroll 8
        for (int d = 0; d < 256; ++d)
            a += qg[d] * w2p[(size_t)d * 1024];
        part[g][ul] = a;
        __syncthreads();
        if (tid < 64) {
            float r = part[0][tid] + part[1][tid] + part[2][tid] + part[3][tid]
                    + b1[u0 + tid] + b2[u0 + tid];
            qp2[b * 1024 + u0 + tid] = r;
        }
    }
}

// ---------------- Kernel 2: fused score+exp+partial-context ----------
// Grid 1024 = 32 b * 32 row-tiles of 64. Block 512 (8 waves, 2/SIMD).
// NEW structure vs r2: NO A-LDS tile. A (values) loaded straight from global
// in fragment order (lane l15 = row, quad = 8-elem k-chunk: each wave load
// covers 16 full 128B lines), fp32->bf16 converted in-register 1 k-step ahead.
// B (W1f) double-buffered in LDS via per-wave global_load_lds DMA (no VGPR
// cost, no barriers: each wave owns [buf][w] 8KB x2; sync = counted vmcnt).
//   LDS: [2][8 waves][8 frags][1KB] = 128KB, red 2KB at +131072.
// Per ks per wave: 8 A-loads(dwordx4,HBM) + 8 B-DMA(1KB,L2) + 32 cvt + 32 MFMA.
// k-loop floor/CU = max(MFMA 14us, B-L2 2MB@135GB/s 15.5us) with A-HBM under.
__global__ __launch_bounds__(512, 2) void k_score(
        const float* __restrict__ values, const __hip_bfloat16* __restrict__ W1f,
        const float* __restrict__ qp2, const float* __restrict__ V,
        float* __restrict__ escore, float* __restrict__ pctx,
        float* __restrict__ pden, float* __restrict__ ctxa) {
    extern __shared__ char smem[];
    float* red = (float*)(smem + 131072);       // [8 stripes][64 rows]

    const int tid = threadIdx.x;
    const int lane = tid & 63, w = tid >> 6;
    const int quad = lane >> 4, l15 = lane & 15;
    const int b = blockIdx.x >> 5, trow0 = (blockIdx.x & 31) << 6;

    // A fragment base: row = trow0 + rt*16 + l15, k-chunk = ks*32 + quad*8
    const float* Ab = values + (size_t)(b * 2048 + trow0 + l15) * 1024 + quad * 8;
    // B fragment source: frag(ut = w*8 + ct, ks) at byte ((ut*32+ks)*1024 + lane*16)
    const char* Bsrc = (const char*)W1f + (size_t)(w * 8) * 32768 + lane * 16;
    char* Bdst = smem + w * 8192;               // + buf*65536 + ct*1024

    f32x4 acc[4][8];
    #pragma unroll
    for (int rt = 0; rt < 4; ++rt)
        #pragma unroll
        for (int ct = 0; ct < 8; ++ct) acc[rt][ct] = (f32x4){0.f, 0.f, 0.f, 0.f};

    // fence any stray earlier vmem so manual vmcnt counts are exact
    asm volatile("s_waitcnt vmcnt(0)" ::: "memory");

    // prologue: A raw loads for ks=0 (order matters: A before DMA so the cvt's
    // compiler-counted wait leaves the DMAs in flight), then B DMA slice 0.
    float4 raw[4][2];
    #pragma unroll
    for (int rt = 0; rt < 4; ++rt) {
        const float* p = Ab + (size_t)rt * 16 * 1024;
        raw[rt][0] = *(const float4*)p;
        raw[rt][1] = *(const float4*)(p + 4);
    }
    #pragma unroll
    for (int ct = 0; ct < 8; ++ct)
        gl_lds16(Bsrc + (size_t)(ct * 32) * 1024, Bdst + ct * 1024);

    #pragma unroll 2
    for (int ks = 0; ks < 32; ++ks) {
        const int cur = ks & 1;
        // convert current A raw (compiler inserts counted vmcnt for raw regs)
        bf16x8 afb[4];
        #pragma unroll
        for (int rt = 0; rt < 4; ++rt) {
            union { uint16_t h[8]; bf16x8 v; } pk;
            pk.h[0] = f2b(raw[rt][0].x); pk.h[1] = f2b(raw[rt][0].y);
            pk.h[2] = f2b(raw[rt][0].z); pk.h[3] = f2b(raw[rt][0].w);
            pk.h[4] = f2b(raw[rt][1].x); pk.h[5] = f2b(raw[rt][1].y);
            pk.h[6] = f2b(raw[rt][1].z); pk.h[7] = f2b(raw[rt][1].w);
            afb[rt] = pk.v;
        }
        if (ks < 31) {
            // issue next A raw loads (HBM, ~1 ks-period of slack)
            #pragma unroll
            for (int rt = 0; rt < 4; ++rt) {
                const float* p = Ab + (size_t)rt * 16 * 1024 + (ks + 1) * 32;
                raw[rt][0] = *(const float4*)p;
                raw[rt][1] = *(const float4*)(p + 4);
            }
            // issue next B DMA slice into the other buffer
            #pragma unroll
            for (int ct = 0; ct < 8; ++ct)
                gl_lds16(Bsrc + (size_t)(ct * 32 + ks + 1) * 1024,
                         Bdst + (cur ^ 1) * 65536 + ct * 1024);
            // outstanding (in-order): DMA(cur)=8 oldest, rawA(nxt)=8, DMA(nxt)=8.
            // vmcnt(16) retires exactly the 8 oldest -> DMA(cur) landed.
            asm volatile("s_waitcnt vmcnt(16)" ::: "memory");
        } else {
            asm volatile("s_waitcnt vmcnt(0)" ::: "memory");
        }
        __builtin_amdgcn_sched_barrier(0);
        #pragma unroll
        for (int ct = 0; ct < 8; ++ct) {
            bf16x8 bq = *(bf16x8*)(smem + cur * 65536 + w * 8192 + ct * 1024 + lane * 16);
            #pragma unroll
            for (int rt = 0; rt < 4; ++rt)
                acc[rt][ct] = __builtin_amdgcn_mfma_f32_16x16x32_bf16(
                    afb[rt], bq, acc[rt][ct], 0, 0, 0);
        }
    }

    // ---- epilogue: tanh(acc + qp2[u]) * V[u], per-lane row partials ----
    float srow[4][4];
    #pragma unroll
    for (int rt = 0; rt < 4; ++rt)
        #pragma unroll
        for (int r = 0; r < 4; ++r) srow[rt][r] = 0.f;
    #pragma unroll
    for (int ct = 0; ct < 8; ++ct) {
        int u = w * 128 + ct * 16 + l15;
        float qv = qp2[b * 1024 + u];
        float vv = V[u];
        #pragma unroll
        for (int rt = 0; rt < 4; ++rt)
            #pragma unroll
            for (int r = 0; r < 4; ++r) {
                float x = acc[rt][ct][r] + qv;
                float e = __expf(2.f * x);
                float t = 1.f - 2.f * __builtin_amdgcn_rcpf(1.f + e);
                srow[rt][r] += t * vv;
            }
    }

    // reduce u: over 16 lanes (l15), then over the 8 wave-stripes via LDS
    #pragma unroll
    for (int rt = 0; rt < 4; ++rt)
        #pragma unroll
        for (int r = 0; r < 4; ++r) {
            float s = srow[rt][r];
            s += __shfl_xor(s, 1, 64);
            s += __shfl_xor(s, 2, 64);
            s += __shfl_xor(s, 4, 64);
            s += __shfl_xor(s, 8, 64);
            srow[rt][r] = s;
        }
    if (l15 == 0) {
        #pragma unroll
        for (int rt = 0; rt < 4; ++rt)
            #pragma unroll
            for (int r = 0; r < 4; ++r)
                red[w * 64 + rt * 16 + quad * 4 + r] = srow[rt][r];
    }
    __syncthreads();

    // ---- fused: e = exp(score); partial denom; partial context ----
    float* wl = (float*)smem;    // alias B region (dead after the barrier)
    if (tid < 64) {
        float s = 0.f;
        #pragma unroll
        for (int k = 0; k < 8; ++k) s += red[k * 64 + tid];
        float e = __expf(s);
        escore[b * 2048 + trow0 + tid] = e;
        wl[tid] = e;
        float dsum = e;
        #pragma unroll
        for (int off = 32; off; off >>= 1) dsum += __shfl_xor(dsum, off, 64);
        if (tid == 0) {
            if (pctx != nullptr) pden[blockIdx.x] = dsum;
            else                 atomicAdd(&pden[b], dsum);
        }
    }
    __syncthreads();

    // weighted sum over this tile's 64 rows; thread owns a float2 of columns.
    // Rows were streamed from global during the k-loop -> L2/L3-warm re-read.
    {
        const float* Vg = values + (size_t)(b * 2048 + trow0) * 1024 + tid * 2;
        float ax = 0.f, ay = 0.f;
        #pragma unroll 8
        for (int t = 0; t < 64; ++t) {
            float wv = wl[t];
            float2 v = *(const float2*)(Vg + (size_t)t * 1024);
            ax += wv * v.x; ay += wv * v.y;
        }
        if (pctx != nullptr) {
            *(float2*)(pctx + (size_t)blockIdx.x * 1024 + tid * 2) = make_float2(ax, ay);
        } else {
            float* o = ctxa + b * 1024 + tid * 2;
            atomicAdd(o + 0, ax);
            atomicAdd(o + 1, ay);
        }
    }
}

// ---------------- Kernel 3: reduce partials, normalize ctx + attw ----
__global__ __launch_bounds__(256) void k_final(const float* __restrict__ pctx,
                                               const float* __restrict__ pden,
                                               const float* __restrict__ escore,
                                               float* __restrict__ out) {
    __shared__ float sinv;
    int b = blockIdx.x, tid = threadIdx.x;
    if (tid == 0) {
        float dsum = 0.f;
        if (pctx != nullptr) {
            #pragma unroll
            for (int t = 0; t < 32; ++t) dsum += pden[b * 32 + t];
        } else {
            dsum = pden[b];
        }
        sinv = 1.f / dsum;
    }
    __syncthreads();
    float inv = sinv;

    int d = tid * 4;
    if (pctx != nullptr) {
        float4 a = {0.f, 0.f, 0.f, 0.f};
        #pragma unroll 8
        for (int t = 0; t < 32; ++t) {
            float4 p = *(const float4*)(pctx + (size_t)(b * 32 + t) * 1024 + d);
            a.x += p.x; a.y += p.y; a.z += p.z; a.w += p.w;
        }
        a.x *= inv; a.y *= inv; a.z *= inv; a.w *= inv;
        *(float4*)(out + b * 1024 + d) = a;
    } else {
        float4 a = *(const float4*)(out + b * 1024 + d);
        a.x *= inv; a.y *= inv; a.z *= inv; a.w *= inv;
        *(float4*)(out + b * 1024 + d) = a;
    }

    // attention weights: e / denom (in small mode escore == out+32768: in-place)
    #pragma unroll
    for (int i = 0; i < 8; ++i) {
        int t = i * 256 + tid;
        out[32768 + b * 2048 + t] = escore[b * 2048 + t] * inv;
    }
}

extern "C" void kernel_launch(void* const* d_in, const int* in_sizes, int n_in,
                              void* d_out, int out_size, void* d_ws, size_t ws_size,
                              hipStream_t stream) {
    const float* query  = (const float*)d_in[0];
    const float* values = (const float*)d_in[1];
    const float* W1 = (const float*)d_in[2];
    const float* b1 = (const float*)d_in[3];
    const float* W2 = (const float*)d_in[4];
    const float* b2 = (const float*)d_in[5];
    const float* V  = (const float*)d_in[6];
    // d_in[7] = bv: adds a constant pre-softmax -> cancels in softmax; unused.

    char* ws = (char*)d_ws;
    __hip_bfloat16* W1f = (__hip_bfloat16*)(ws + WS_W1F);
    float* qp2 = (float*)(ws + WS_QP2);
    float* out = (float*)d_out;

    const bool big = ws_size >= (size_t)WS_NEED;
    float* escore = big ? (float*)(ws + WS_ESC)  : out + 32768;
    float* pctx   = big ? (float*)(ws + WS_PCTX) : nullptr;
    float* pden   = big ? (float*)(ws + WS_PDEN) : (float*)(ws + WS_ESC);
    float* zctx   = big ? nullptr : out;
    float* zden   = big ? nullptr : pden;

    (void)hipFuncSetAttribute((const void*)k_score,
                              hipFuncAttributeMaxDynamicSharedMemorySize, 133120);

    k_prep<<<768, 256, 0, stream>>>(W1, query, W2, b1, b2, W1f, qp2, zctx, zden);
    k_score<<<1024, 512, 133120, stream>>>(values, W1f, qp2, V, escore, pctx, pden, out);
    k_final<<<32, 256, 0, stream>>>(pctx, pden, escore, out);
}

// Round 4
// 557.914 us; speedup vs baseline: 1.1950x; 1.1950x over previous
//
#include <hip/hip_runtime.h>
#include <hip/hip_bf16.h>
#include <stdint.h>

// Problem: B=32, T=2048, D=1024, U=1024, all fp32 in/out.
// out = [context 32*1024, attention_weights 32*2048]
//
// ws layout (big mode, needs WS_NEED bytes):
//   [0, 2MB)            W1f bf16 — W1 packed in MFMA B-fragment order
//   [2MB, +128KB)       qp2 fp32 [B][U] = query@W2 + b2 + b1
//   [+128KB, +256KB)    escore fp32 [B][T] = exp(score) (unnormalized)
//   [+256KB, +4MB)      pctx fp32 [1024 blocks][1024] partial contexts
//   [+4MB, +4KB)        pden fp32 [1024] partial softmax denominators
//
// small-ws fallback (fits the previously-verified 2.49MB footprint):
//   escore -> out attw region; pctx -> atomicAdd into out ctx (zeroed in prep);
//   pden -> 32 floats at WS_ESC (atomicAdd, zeroed in prep)
#define WS_W1F   0
#define WS_QP2   2097152
#define WS_ESC   (WS_QP2 + 131072)
#define WS_PCTX  (WS_ESC + 262144)
#define WS_PDEN  (WS_PCTX + 4194304)
#define WS_NEED  (WS_PDEN + 4096)

typedef __attribute__((ext_vector_type(8))) short bf16x8;
typedef __attribute__((ext_vector_type(4))) float f32x4;

__device__ inline uint16_t f2b(float f) {
    __hip_bfloat16 h = __float2bfloat16(f);
    return *reinterpret_cast<uint16_t*>(&h);
}

// ---------------- Kernel 1: prep = W1 repack + qp2 (+ optional zeroing) -----
__global__ __launch_bounds__(256) void k_prep(const float* __restrict__ W1,
                                              const float* __restrict__ query,
                                              const float* __restrict__ W2,
                                              const float* __restrict__ b1,
                                              const float* __restrict__ b2,
                                              __hip_bfloat16* __restrict__ W1f,
                                              float* __restrict__ qp2,
                                              float* __restrict__ zctx,
                                              float* __restrict__ zden) {
    __shared__ float qs[1024];
    __shared__ float part[4][64];
    int blk = blockIdx.x, tid = threadIdx.x;
    if (blk < 256) {
        int lane = tid & 63, fi = tid >> 6;
        int l15 = lane & 15, quad = lane >> 4;
        #pragma unroll
        for (int p = 0; p < 2; ++p) {
            int frag = blk * 8 + p * 4 + fi;      // 0..2047
            int ut = frag >> 5, ks = frag & 31;
            union { uint16_t h[8]; int4 v; } pk;
            #pragma unroll
            for (int j = 0; j < 8; ++j) {
                float x = W1[(size_t)(ks * 32 + quad * 8 + j) * 1024 + ut * 16 + l15];
                pk.h[j] = f2b(x);
            }
            *(int4*)((char*)W1f + (size_t)frag * 1024 + lane * 16) = pk.v;
        }
    } else {
        int bq = blk - 256;            // 0..511
        int b = bq >> 4, us = bq & 15, u0 = us * 64;
        if (zctx != nullptr && us == 0) {
            *(float4*)(zctx + b * 1024 + tid * 4) = make_float4(0.f, 0.f, 0.f, 0.f);
            if (b == 0 && tid < 32) zden[tid] = 0.f;
        }
        const float* q = query + b * 1024;
        #pragma unroll
        for (int i = 0; i < 4; ++i) qs[i * 256 + tid] = q[i * 256 + tid];
        __syncthreads();
        int ul = tid & 63, g = tid >> 6;       // 4 d-groups x 64 u
        float a = 0.f;
        const float* w2p = W2 + (size_t)(g * 256) * 1024 + u0 + ul;
        const float* qg = qs + g * 256;
        #pragma unroll 8
        for (int d = 0; d < 256; ++d)
            a += qg[d] * w2p[(size_t)d * 1024];
        part[g][ul] = a;
        __syncthreads();
        if (tid < 64) {
            float r = part[0][tid] + part[1][tid] + part[2][tid] + part[3][tid]
                    + b1[u0 + tid] + b2[u0 + tid];
            qp2[b * 1024 + u0 + tid] = r;
        }
    }
}

// ---------------- Kernel 2: fused score+exp+partial-context ----------
// Grid 1024 = 32 b * 32 row-tiles of 64. Block 512 (8 waves, 2/SIMD).
// r2 structure (LDS-A shared across waves, B per-lane dbuf regs) BUT the
// 128KB A-stage is now INCREMENTAL: per k-iter, stage the (ks+1) 32-k chunk
// (8KB fp32 -> 4KB bf16 LDS, one float4/thread, 2-chunk reg lookahead).
// Per-iter sync = lgkmcnt(0) + raw s_barrier (NO vmcnt drain: in-flight
// global loads survive the barrier). Same XOR-swizzled layout as r2 ->
// MFMA-side ds_read pattern unchanged (measured 0 conflicts).
__global__ __launch_bounds__(512, 1) void k_score(
        const float* __restrict__ values, const __hip_bfloat16* __restrict__ W1f,
        const float* __restrict__ qp2, const float* __restrict__ V,
        float* __restrict__ escore, float* __restrict__ pctx,
        float* __restrict__ pden, float* __restrict__ ctxa) {
    extern __shared__ char smem[];
    uint16_t* Al = (uint16_t*)smem;             // 64 x 1024 bf16 (swizzled)
    float* red = (float*)(smem + 131072);       // [8 stripes][64 rows]

    const int tid = threadIdx.x;
    const int lane = tid & 63, w = tid >> 6;
    const int quad = lane >> 4, l15 = lane & 15;
    const int b = blockIdx.x >> 5, trow0 = (blockIdx.x & 31) << 6;

    const float* Ag = values + (size_t)(b * 2048 + trow0) * 1024;

    // stage addressing: thread t covers row=t>>3, part=t&7 (4 floats of the
    // 32-k chunk). Global: full 128B lines per row (8 lanes x 16B).
    const int srow = tid >> 3, spart = tid & 7;
    const float* sgp = Ag + (size_t)srow * 1024 + spart * 4;
    // LDS write: c = ch*4 + (spart>>1), pos = (c&112)|((c&15)^(srow&15)),
    // byte = srow*2048 + pos*16 + (spart&1)*8   (quarter-wave: 2-way, free)
    char* sbase = (char*)smem + srow * 2048 + (spart & 1) * 8;
    const int chalf = spart >> 1;

    // per-lane B fragment base: frag(ut = w*8 + ct, ks) at byte (ut*32+ks)*1024
    const char* Bbase = (const char*)W1f + (size_t)(w * 8) * 32768 + lane * 16;

    f32x4 acc[4][8];
    #pragma unroll
    for (int rt = 0; rt < 4; ++rt)
        #pragma unroll
        for (int ct = 0; ct < 8; ++ct) acc[rt][ct] = (f32x4){0.f, 0.f, 0.f, 0.f};

    bf16x8 bfr[2][8];
    float4 g0, g1;

    // ---- prologue: chunk0 -> LDS, chunk1 -> regs, B(ks=0) -> regs ----
    g0 = *(const float4*)(sgp);                     // chunk 0
    #pragma unroll
    for (int ct = 0; ct < 8; ++ct)
        bfr[0][ct] = *(const bf16x8*)(Bbase + (size_t)(ct * 32) * 1024);
    {   // write chunk 0
        int c = chalf;                              // ch=0
        int pos = (c & 112) | ((c & 15) ^ (srow & 15));
        union { uint16_t h[4]; uint2 u; } pk;
        pk.h[0] = f2b(g0.x); pk.h[1] = f2b(g0.y);
        pk.h[2] = f2b(g0.z); pk.h[3] = f2b(g0.w);
        *(uint2*)(sbase + pos * 16) = pk.u;
    }
    g1 = *(const float4*)(sgp + 32);                // chunk 1
    asm volatile("s_waitcnt lgkmcnt(0)" ::: "memory");
    __builtin_amdgcn_s_barrier();
    __builtin_amdgcn_sched_barrier(0);

    #pragma unroll 2
    for (int ks = 0; ks < 32; ++ks) {
        const int cur = ks & 1;
        // af reads for chunk ks (post-barrier: chunk ks is visible)
        bf16x8 af[4];
        {
            int cb = ks * 4 + quad;
            int pos = (cb & 112) | ((cb & 15) ^ l15);
            #pragma unroll
            for (int rt = 0; rt < 4; ++rt)
                af[rt] = *(bf16x8*)(Al + (rt * 16 + l15) * 1024 + pos * 8);
        }
        if (ks < 31) {
            // write chunk ks+1 from lookahead regs (ch c lives in g[c&1])
            float4 v = (ks & 1) ? g0 : g1;
            int c = (ks + 1) * 4 + chalf;
            int pos = (c & 112) | ((c & 15) ^ (srow & 15));
            union { uint16_t h[4]; uint2 u; } pk;
            pk.h[0] = f2b(v.x); pk.h[1] = f2b(v.y);
            pk.h[2] = f2b(v.z); pk.h[3] = f2b(v.w);
            *(uint2*)(sbase + pos * 16) = pk.u;
        }
        if (ks < 30) {
            // issue global load of chunk ks+2 into the freed slot
            float4 t = *(const float4*)(sgp + (ks + 2) * 32);
            if ((ks & 1) == 0) g0 = t; else g1 = t;
        }
        if (ks < 31) {
            #pragma unroll
            for (int ct = 0; ct < 8; ++ct)
                bfr[cur ^ 1][ct] = *(const bf16x8*)(Bbase + (size_t)(ct * 32 + ks + 1) * 1024);
        }
        #pragma unroll
        for (int ct = 0; ct < 8; ++ct)
            #pragma unroll
            for (int rt = 0; rt < 4; ++rt)
                acc[rt][ct] = __builtin_amdgcn_mfma_f32_16x16x32_bf16(
                    af[rt], bfr[cur][ct], acc[rt][ct], 0, 0, 0);
        asm volatile("s_waitcnt lgkmcnt(0)" ::: "memory");
        __builtin_amdgcn_s_barrier();
        __builtin_amdgcn_sched_barrier(0);
    }

    // ---- epilogue: tanh(acc + qp2[u]) * V[u], per-lane row partials ----
    float srw[4][4];
    #pragma unroll
    for (int rt = 0; rt < 4; ++rt)
        #pragma unroll
        for (int r = 0; r < 4; ++r) srw[rt][r] = 0.f;
    #pragma unroll
    for (int ct = 0; ct < 8; ++ct) {
        int u = w * 128 + ct * 16 + l15;
        float qv = qp2[b * 1024 + u];
        float vv = V[u];
        #pragma unroll
        for (int rt = 0; rt < 4; ++rt)
            #pragma unroll
            for (int r = 0; r < 4; ++r) {
                float x = acc[rt][ct][r] + qv;
                float e = __expf(2.f * x);
                float t = 1.f - 2.f * __builtin_amdgcn_rcpf(1.f + e);
                srw[rt][r] += t * vv;
            }
    }

    // reduce u: over 16 lanes (l15), then over the 8 wave-stripes via LDS
    #pragma unroll
    for (int rt = 0; rt < 4; ++rt)
        #pragma unroll
        for (int r = 0; r < 4; ++r) {
            float s = srw[rt][r];
            s += __shfl_xor(s, 1, 64);
            s += __shfl_xor(s, 2, 64);
            s += __shfl_xor(s, 4, 64);
            s += __shfl_xor(s, 8, 64);
            srw[rt][r] = s;
        }
    if (l15 == 0) {
        #pragma unroll
        for (int rt = 0; rt < 4; ++rt)
            #pragma unroll
            for (int r = 0; r < 4; ++r)
                red[w * 64 + rt * 16 + quad * 4 + r] = srw[rt][r];
    }
    __syncthreads();

    // ---- fused: e = exp(score); partial denom; partial context ----
    float* wl = (float*)smem;    // alias A region (dead after the barrier)
    if (tid < 64) {
        float s = 0.f;
        #pragma unroll
        for (int k = 0; k < 8; ++k) s += red[k * 64 + tid];
        float e = __expf(s);
        escore[b * 2048 + trow0 + tid] = e;
        wl[tid] = e;
        float dsum = e;
        #pragma unroll
        for (int off = 32; off; off >>= 1) dsum += __shfl_xor(dsum, off, 64);
        if (tid == 0) {
            if (pctx != nullptr) pden[blockIdx.x] = dsum;
            else                 atomicAdd(&pden[b], dsum);
        }
    }
    __syncthreads();

    // weighted sum over this tile's 64 rows (L2/L3-warm re-read of values)
    {
        const float* Vg = values + (size_t)(b * 2048 + trow0) * 1024 + tid * 2;
        float ax = 0.f, ay = 0.f;
        #pragma unroll 8
        for (int t = 0; t < 64; ++t) {
            float wv = wl[t];
            float2 v = *(const float2*)(Vg + (size_t)t * 1024);
            ax += wv * v.x; ay += wv * v.y;
        }
        if (pctx != nullptr) {
            *(float2*)(pctx + (size_t)blockIdx.x * 1024 + tid * 2) = make_float2(ax, ay);
        } else {
            float* o = ctxa + b * 1024 + tid * 2;
            atomicAdd(o + 0, ax);
            atomicAdd(o + 1, ay);
        }
    }
}

// ---------------- Kernel 3: reduce partials, normalize ctx + attw ----
__global__ __launch_bounds__(256) void k_final(const float* __restrict__ pctx,
                                               const float* __restrict__ pden,
                                               const float* __restrict__ escore,
                                               float* __restrict__ out) {
    __shared__ float sinv;
    int b = blockIdx.x, tid = threadIdx.x;
    if (tid == 0) {
        float dsum = 0.f;
        if (pctx != nullptr) {
            #pragma unroll
            for (int t = 0; t < 32; ++t) dsum += pden[b * 32 + t];
        } else {
            dsum = pden[b];
        }
        sinv = 1.f / dsum;
    }
    __syncthreads();
    float inv = sinv;

    int d = tid * 4;
    if (pctx != nullptr) {
        float4 a = {0.f, 0.f, 0.f, 0.f};
        #pragma unroll 8
        for (int t = 0; t < 32; ++t) {
            float4 p = *(const float4*)(pctx + (size_t)(b * 32 + t) * 1024 + d);
            a.x += p.x; a.y += p.y; a.z += p.z; a.w += p.w;
        }
        a.x *= inv; a.y *= inv; a.z *= inv; a.w *= inv;
        *(float4*)(out + b * 1024 + d) = a;
    } else {
        float4 a = *(const float4*)(out + b * 1024 + d);
        a.x *= inv; a.y *= inv; a.z *= inv; a.w *= inv;
        *(float4*)(out + b * 1024 + d) = a;
    }

    // attention weights: e / denom (small mode: escore==out+32768, in-place)
    #pragma unroll
    for (int i = 0; i < 8; ++i) {
        int t = i * 256 + tid;
        out[32768 + b * 2048 + t] = escore[b * 2048 + t] * inv;
    }
}

extern "C" void kernel_launch(void* const* d_in, const int* in_sizes, int n_in,
                              void* d_out, int out_size, void* d_ws, size_t ws_size,
                              hipStream_t stream) {
    const float* query  = (const float*)d_in[0];
    const float* values = (const float*)d_in[1];
    const float* W1 = (const float*)d_in[2];
    const float* b1 = (const float*)d_in[3];
    const float* W2 = (const float*)d_in[4];
    const float* b2 = (const float*)d_in[5];
    const float* V  = (const float*)d_in[6];
    // d_in[7] = bv: constant pre-softmax -> cancels in softmax; unused.

    char* ws = (char*)d_ws;
    __hip_bfloat16* W1f = (__hip_bfloat16*)(ws + WS_W1F);
    float* qp2 = (float*)(ws + WS_QP2);
    float* out = (float*)d_out;

    const bool big = ws_size >= (size_t)WS_NEED;
    float* escore = big ? (float*)(ws + WS_ESC)  : out + 32768;
    float* pctx   = big ? (float*)(ws + WS_PCTX) : nullptr;
    float* pden   = big ? (float*)(ws + WS_PDEN) : (float*)(ws + WS_ESC);
    float* zctx   = big ? nullptr : out;
    float* zden   = big ? nullptr : pden;

    (void)hipFuncSetAttribute((const void*)k_score,
                              hipFuncAttributeMaxDynamicSharedMemorySize, 133120);

    k_prep<<<768, 256, 0, stream>>>(W1, query, W2, b1, b2, W1f, qp2, zctx, zden);
    k_score<<<1024, 512, 133120, stream>>>(values, W1f, qp2, V, escore, pctx, pden, out);
    k_final<<<32, 256, 0, stream>>>(pctx, pden, escore, out);
}

// Round 5
// 529.007 us; speedup vs baseline: 1.2603x; 1.0546x over previous
//
#include <hip/hip_runtime.h>
#include <hip/hip_bf16.h>
#include <stdint.h>

// Problem: B=32, T=2048, D=1024, U=1024, all fp32 in/out.
// out = [context 32*1024, attention_weights 32*2048]
//
// ws layout (big mode, needs WS_NEED bytes):
//   [0, 2MB)            W1f bf16 — W1 packed in MFMA B-fragment order
//   [2MB, +128KB)       qp2 fp32 [B][U] = query@W2 + b2 + b1
//   [+128KB, +256KB)    escore fp32 [B][T] = exp(score) (unnormalized)
//   [+256KB, +4MB)      pctx fp32 [1024 blocks][1024] partial contexts
//   [+4MB, +4KB)        pden fp32 [1024] partial softmax denominators
//
// small-ws fallback (fits the previously-verified 2.49MB footprint):
//   escore -> out attw region; pctx -> atomicAdd into out ctx (zeroed in prep);
//   pden -> 32 floats at WS_ESC (atomicAdd, zeroed in prep)
#define WS_W1F   0
#define WS_QP2   2097152
#define WS_ESC   (WS_QP2 + 131072)
#define WS_PCTX  (WS_ESC + 262144)
#define WS_PDEN  (WS_PCTX + 4194304)
#define WS_NEED  (WS_PDEN + 4096)

typedef __attribute__((ext_vector_type(8))) short bf16x8;
typedef __attribute__((ext_vector_type(4))) float f32x4;

__device__ inline uint16_t f2b(float f) {
    __hip_bfloat16 h = __float2bfloat16(f);
    return *reinterpret_cast<uint16_t*>(&h);
}

// ---------------- Kernel 1: prep = W1 repack + qp2 (+ optional zeroing) -----
// blocks 0..255: repack 8 fragments each (2048 fragments of 1KB total)
// blocks 256..767: qp2 on (b, u-slice of 64): 512 blocks (proven win in r4).
__global__ __launch_bounds__(256) void k_prep(const float* __restrict__ W1,
                                              const float* __restrict__ query,
                                              const float* __restrict__ W2,
                                              const float* __restrict__ b1,
                                              const float* __restrict__ b2,
                                              __hip_bfloat16* __restrict__ W1f,
                                              float* __restrict__ qp2,
                                              float* __restrict__ zctx,
                                              float* __restrict__ zden) {
    __shared__ float qs[1024];
    __shared__ float part[4][64];
    int blk = blockIdx.x, tid = threadIdx.x;
    if (blk < 256) {
        int lane = tid & 63, fi = tid >> 6;
        int l15 = lane & 15, quad = lane >> 4;
        #pragma unroll
        for (int p = 0; p < 2; ++p) {
            int frag = blk * 8 + p * 4 + fi;      // 0..2047
            int ut = frag >> 5, ks = frag & 31;
            union { uint16_t h[8]; int4 v; } pk;
            #pragma unroll
            for (int j = 0; j < 8; ++j) {
                float x = W1[(size_t)(ks * 32 + quad * 8 + j) * 1024 + ut * 16 + l15];
                pk.h[j] = f2b(x);
            }
            *(int4*)((char*)W1f + (size_t)frag * 1024 + lane * 16) = pk.v;
        }
    } else {
        int bq = blk - 256;            // 0..511
        int b = bq >> 4, us = bq & 15, u0 = us * 64;
        if (zctx != nullptr && us == 0) {
            *(float4*)(zctx + b * 1024 + tid * 4) = make_float4(0.f, 0.f, 0.f, 0.f);
            if (b == 0 && tid < 32) zden[tid] = 0.f;
        }
        const float* q = query + b * 1024;
        #pragma unroll
        for (int i = 0; i < 4; ++i) qs[i * 256 + tid] = q[i * 256 + tid];
        __syncthreads();
        int ul = tid & 63, g = tid >> 6;       // 4 d-groups x 64 u
        float a = 0.f;
        const float* w2p = W2 + (size_t)(g * 256) * 1024 + u0 + ul;
        const float* qg = qs + g * 256;
        #pragma unroll 8
        for (int d = 0; d < 256; ++d)
            a += qg[d] * w2p[(size_t)d * 1024];
        part[g][ul] = a;
        __syncthreads();
        if (tid < 64) {
            float r = part[0][tid] + part[1][tid] + part[2][tid] + part[3][tid]
                    + b1[u0 + tid] + b2[u0 + tid];
            qp2[b * 1024 + u0 + tid] = r;
        }
    }
}

// ---------------- Kernel 2: fused score+exp+partial-context ----------
// Grid 1024 = 32 b * 32 row-tiles of 64. Block 512 (8 waves, 2/SIMD).
// r2 structure (bulk A-stage in LDS, B reg-dbuf from global, barrier-free
// k-loop) + r5 change: PINNED schedule. Per iter the 8 B prefetch loads are
// split into two 4-load groups, each followed by a sched_barrier(0) fence and
// a 16-MFMA cluster wrapped in s_setprio(1). This keeps each load group one
// full MFMA-cluster (~600cy) ahead of its use so L2 latency stays hidden
// (the compiler otherwise sinks loads toward uses; T14/rule-18).
__global__ __launch_bounds__(512, 1) void k_score(
        const float* __restrict__ values, const __hip_bfloat16* __restrict__ W1f,
        const float* __restrict__ qp2, const float* __restrict__ V,
        float* __restrict__ escore, float* __restrict__ pctx,
        float* __restrict__ pden, float* __restrict__ ctxa) {
    extern __shared__ char smem[];
    uint16_t* Al = (uint16_t*)smem;             // 64 x 1024 bf16 (swizzled)
    float* red = (float*)(smem + 131072);       // [8 stripes][64 rows]

    const int tid = threadIdx.x;
    const int lane = tid & 63, w = tid >> 6;
    const int quad = lane >> 4, l15 = lane & 15;
    const int b = blockIdx.x >> 5, trow0 = (blockIdx.x & 31) << 6;

    // ---- stage A: values[b, trow0..+64, :] fp32 -> bf16 LDS (once) ----
    const float* Ag = values + (size_t)(b * 2048 + trow0) * 1024;
    #pragma unroll
    for (int i = 0; i < 16; ++i) {
        int id = i * 512 + tid;
        int row = id >> 7, c = id & 127;
        const float* src = Ag + (size_t)row * 1024 + c * 8;
        float4 v0 = *(const float4*)src;
        float4 v1 = *(const float4*)(src + 4);
        union { uint16_t h[8]; int4 v; } pk;
        pk.h[0]=f2b(v0.x); pk.h[1]=f2b(v0.y); pk.h[2]=f2b(v0.z); pk.h[3]=f2b(v0.w);
        pk.h[4]=f2b(v1.x); pk.h[5]=f2b(v1.y); pk.h[6]=f2b(v1.z); pk.h[7]=f2b(v1.w);
        int pos = (c & 112) | ((c & 15) ^ (row & 15));
        *(int4*)(Al + (size_t)row * 1024 + pos * 8) = pk.v;
    }
    __syncthreads();   // only barrier before the final reduction

    // per-lane fragment base: frag(ut = w*8 + ct, ks) at byte (ut*32+ks)*1024
    const char* Bbase = (const char*)W1f + (size_t)(w * 8) * 32768 + lane * 16;

    f32x4 acc[4][8];
    #pragma unroll
    for (int rt = 0; rt < 4; ++rt)
        #pragma unroll
        for (int ct = 0; ct < 8; ++ct) acc[rt][ct] = (f32x4){0.f, 0.f, 0.f, 0.f};

    bf16x8 af[2][4], bfr[2][8];
    {   // prologue: ks = 0
        int pos = (quad & 15) ^ l15;   // cb = quad
        #pragma unroll
        for (int rt = 0; rt < 4; ++rt)
            af[0][rt] = *(bf16x8*)(Al + (rt * 16 + l15) * 1024 + pos * 8);
        #pragma unroll
        for (int ct = 0; ct < 8; ++ct)
            bfr[0][ct] = *(const bf16x8*)(Bbase + (size_t)(ct * 32) * 1024);
    }

    #pragma unroll 2
    for (int ks = 0; ks < 32; ++ks) {
        const int cur = ks & 1, nxt = cur ^ 1;
        // ---- issue next-iter af (LDS) + first half of next-iter B ----
        if (ks < 31) {
            int cb = (ks + 1) * 4 + quad;
            int pos = (cb & 112) | ((cb & 15) ^ l15);
            #pragma unroll
            for (int rt = 0; rt < 4; ++rt)
                af[nxt][rt] = *(bf16x8*)(Al + (rt * 16 + l15) * 1024 + pos * 8);
            #pragma unroll
            for (int ct = 0; ct < 4; ++ct)
                bfr[nxt][ct] = *(const bf16x8*)(Bbase + (size_t)(ct * 32 + ks + 1) * 1024);
        }
        __builtin_amdgcn_sched_barrier(0);
        // ---- MFMA cluster 1: ct 0..3 ----
        __builtin_amdgcn_s_setprio(1);
        #pragma unroll
        for (int ct = 0; ct < 4; ++ct)
            #pragma unroll
            for (int rt = 0; rt < 4; ++rt)
                acc[rt][ct] = __builtin_amdgcn_mfma_f32_16x16x32_bf16(
                    af[cur][rt], bfr[cur][ct], acc[rt][ct], 0, 0, 0);
        __builtin_amdgcn_s_setprio(0);
        __builtin_amdgcn_sched_barrier(0);
        // ---- issue second half of next-iter B ----
        if (ks < 31) {
            #pragma unroll
            for (int ct = 4; ct < 8; ++ct)
                bfr[nxt][ct] = *(const bf16x8*)(Bbase + (size_t)(ct * 32 + ks + 1) * 1024);
        }
        __builtin_amdgcn_sched_barrier(0);
        // ---- MFMA cluster 2: ct 4..7 ----
        __builtin_amdgcn_s_setprio(1);
        #pragma unroll
        for (int ct = 4; ct < 8; ++ct)
            #pragma unroll
            for (int rt = 0; rt < 4; ++rt)
                acc[rt][ct] = __builtin_amdgcn_mfma_f32_16x16x32_bf16(
                    af[cur][rt], bfr[cur][ct], acc[rt][ct], 0, 0, 0);
        __builtin_amdgcn_s_setprio(0);
        __builtin_amdgcn_sched_barrier(0);
    }

    // ---- epilogue: tanh(acc + qp2[u]) * V[u], per-lane row partials ----
    float srow[4][4];
    #pragma unroll
    for (int rt = 0; rt < 4; ++rt)
        #pragma unroll
        for (int r = 0; r < 4; ++r) srow[rt][r] = 0.f;
    #pragma unroll
    for (int ct = 0; ct < 8; ++ct) {
        int u = w * 128 + ct * 16 + l15;
        float qv = qp2[b * 1024 + u];
        float vv = V[u];
        #pragma unroll
        for (int rt = 0; rt < 4; ++rt)
            #pragma unroll
            for (int r = 0; r < 4; ++r) {
                float x = acc[rt][ct][r] + qv;
                float e = __expf(2.f * x);
                float t = 1.f - 2.f * __builtin_amdgcn_rcpf(1.f + e);
                srow[rt][r] += t * vv;
            }
    }

    // reduce u: over 16 lanes (l15), then over the 8 wave-stripes via LDS
    #pragma unroll
    for (int rt = 0; rt < 4; ++rt)
        #pragma unroll
        for (int r = 0; r < 4; ++r) {
            float s = srow[rt][r];
            s += __shfl_xor(s, 1, 64);
            s += __shfl_xor(s, 2, 64);
            s += __shfl_xor(s, 4, 64);
            s += __shfl_xor(s, 8, 64);
            srow[rt][r] = s;
        }
    if (l15 == 0) {
        #pragma unroll
        for (int rt = 0; rt < 4; ++rt)
            #pragma unroll
            for (int r = 0; r < 4; ++r)
                red[w * 64 + rt * 16 + quad * 4 + r] = srow[rt][r];
    }
    __syncthreads();

    // ---- fused: e = exp(score); partial denom; partial context ----
    float* wl = (float*)smem;    // alias A region (dead after the barrier)
    if (tid < 64) {
        float s = 0.f;
        #pragma unroll
        for (int k = 0; k < 8; ++k) s += red[k * 64 + tid];
        float e = __expf(s);
        escore[b * 2048 + trow0 + tid] = e;
        wl[tid] = e;
        float dsum = e;
        #pragma unroll
        for (int off = 32; off; off >>= 1) dsum += __shfl_xor(dsum, off, 64);
        if (tid == 0) {
            if (pctx != nullptr) pden[blockIdx.x] = dsum;
            else                 atomicAdd(&pden[b], dsum);
        }
    }
    __syncthreads();

    // weighted sum over this tile's 64 rows (L2/L3-warm re-read of values)
    {
        const float* Vg = values + (size_t)(b * 2048 + trow0) * 1024 + tid * 2;
        float ax = 0.f, ay = 0.f;
        #pragma unroll 8
        for (int t = 0; t < 64; ++t) {
            float wv = wl[t];
            float2 v = *(const float2*)(Vg + (size_t)t * 1024);
            ax += wv * v.x; ay += wv * v.y;
        }
        if (pctx != nullptr) {
            *(float2*)(pctx + (size_t)blockIdx.x * 1024 + tid * 2) = make_float2(ax, ay);
        } else {
            float* o = ctxa + b * 1024 + tid * 2;
            atomicAdd(o + 0, ax);
            atomicAdd(o + 1, ay);
        }
    }
}

// ---------------- Kernel 3: reduce partials, normalize ctx + attw ----
__global__ __launch_bounds__(256) void k_final(const float* __restrict__ pctx,
                                               const float* __restrict__ pden,
                                               const float* __restrict__ escore,
                                               float* __restrict__ out) {
    __shared__ float sinv;
    int b = blockIdx.x, tid = threadIdx.x;
    if (tid == 0) {
        float dsum = 0.f;
        if (pctx != nullptr) {
            #pragma unroll
            for (int t = 0; t < 32; ++t) dsum += pden[b * 32 + t];
        } else {
            dsum = pden[b];
        }
        sinv = 1.f / dsum;
    }
    __syncthreads();
    float inv = sinv;

    int d = tid * 4;
    if (pctx != nullptr) {
        float4 a = {0.f, 0.f, 0.f, 0.f};
        #pragma unroll 8
        for (int t = 0; t < 32; ++t) {
            float4 p = *(const float4*)(pctx + (size_t)(b * 32 + t) * 1024 + d);
            a.x += p.x; a.y += p.y; a.z += p.z; a.w += p.w;
        }
        a.x *= inv; a.y *= inv; a.z *= inv; a.w *= inv;
        *(float4*)(out + b * 1024 + d) = a;
    } else {
        float4 a = *(const float4*)(out + b * 1024 + d);
        a.x *= inv; a.y *= inv; a.z *= inv; a.w *= inv;
        *(float4*)(out + b * 1024 + d) = a;
    }

    // attention weights: e / denom (small mode: escore==out+32768, in-place)
    #pragma unroll
    for (int i = 0; i < 8; ++i) {
        int t = i * 256 + tid;
        out[32768 + b * 2048 + t] = escore[b * 2048 + t] * inv;
    }
}

extern "C" void kernel_launch(void* const* d_in, const int* in_sizes, int n_in,
                              void* d_out, int out_size, void* d_ws, size_t ws_size,
                              hipStream_t stream) {
    const float* query  = (const float*)d_in[0];
    const float* values = (const float*)d_in[1];
    const float* W1 = (const float*)d_in[2];
    const float* b1 = (const float*)d_in[3];
    const float* W2 = (const float*)d_in[4];
    const float* b2 = (const float*)d_in[5];
    const float* V  = (const float*)d_in[6];
    // d_in[7] = bv: constant pre-softmax -> cancels in softmax; unused.

    char* ws = (char*)d_ws;
    __hip_bfloat16* W1f = (__hip_bfloat16*)(ws + WS_W1F);
    float* qp2 = (float*)(ws + WS_QP2);
    float* out = (float*)d_out;

    const bool big = ws_size >= (size_t)WS_NEED;
    float* escore = big ? (float*)(ws + WS_ESC)  : out + 32768;
    float* pctx   = big ? (float*)(ws + WS_PCTX) : nullptr;
    float* pden   = big ? (float*)(ws + WS_PDEN) : (float*)(ws + WS_ESC);
    float* zctx   = big ? nullptr : out;
    float* zden   = big ? nullptr : pden;

    (void)hipFuncSetAttribute((const void*)k_score,
                              hipFuncAttributeMaxDynamicSharedMemorySize, 133120);

    k_prep<<<768, 256, 0, stream>>>(W1, query, W2, b1, b2, W1f, qp2, zctx, zden);
    k_score<<<1024, 512, 133120, stream>>>(values, W1f, qp2, V, escore, pctx, pden, out);
    k_final<<<32, 256, 0, stream>>>(pctx, pden, escore, out);
}

// Round 6
// 519.824 us; speedup vs baseline: 1.2825x; 1.0177x over previous
//
#include <hip/hip_runtime.h>
#include <hip/hip_bf16.h>
#include <stdint.h>

// Problem: B=32, T=2048, D=1024, U=1024, all fp32 in/out.
// out = [context 32*1024, attention_weights 32*2048]
//
// ws layout (big mode, needs WS_NEED bytes):
//   [0, 2MB)            W1f bf16 — W1 packed in MFMA B-fragment order
//   [2MB, +128KB)       qp2 fp32 [B][U] = query@W2 + b2 + b1
//   [+128KB, +256KB)    escore fp32 [B][T] = exp(score) (unnormalized)
//   [+256KB, +4MB)      pctx fp32 [1024 blocks][1024] partial contexts
//   [+4MB, +4KB)        pden fp32 [1024] partial softmax denominators
//
// small-ws fallback (fits the previously-verified 2.49MB footprint):
//   escore -> out attw region; pctx -> atomicAdd into out ctx (zeroed in prep);
//   pden -> 32 floats at WS_ESC (atomicAdd, zeroed in prep)
#define WS_W1F   0
#define WS_QP2   2097152
#define WS_ESC   (WS_QP2 + 131072)
#define WS_PCTX  (WS_ESC + 262144)
#define WS_PDEN  (WS_PCTX + 4194304)
#define WS_NEED  (WS_PDEN + 4096)

typedef __attribute__((ext_vector_type(8))) short bf16x8;
typedef __attribute__((ext_vector_type(4))) float f32x4;

__device__ inline uint16_t f2b(float f) {
    __hip_bfloat16 h = __float2bfloat16(f);
    return *reinterpret_cast<uint16_t*>(&h);
}

// ---------------- Kernel 1: prep = W1 repack + qp2 (+ optional zeroing) -----
// blocks 0..255: repack 8 fragments each (2048 fragments of 1KB total)
// blocks 256..767: qp2 on (b, u-slice of 64): 512 blocks (proven win in r4).
__global__ __launch_bounds__(256) void k_prep(const float* __restrict__ W1,
                                              const float* __restrict__ query,
                                              const float* __restrict__ W2,
                                              const float* __restrict__ b1,
                                              const float* __restrict__ b2,
                                              __hip_bfloat16* __restrict__ W1f,
                                              float* __restrict__ qp2,
                                              float* __restrict__ zctx,
                                              float* __restrict__ zden) {
    __shared__ float qs[1024];
    __shared__ float part[4][64];
    int blk = blockIdx.x, tid = threadIdx.x;
    if (blk < 256) {
        int lane = tid & 63, fi = tid >> 6;
        int l15 = lane & 15, quad = lane >> 4;
        #pragma unroll
        for (int p = 0; p < 2; ++p) {
            int frag = blk * 8 + p * 4 + fi;      // 0..2047
            int ut = frag >> 5, ks = frag & 31;
            union { uint16_t h[8]; int4 v; } pk;
            #pragma unroll
            for (int j = 0; j < 8; ++j) {
                float x = W1[(size_t)(ks * 32 + quad * 8 + j) * 1024 + ut * 16 + l15];
                pk.h[j] = f2b(x);
            }
            *(int4*)((char*)W1f + (size_t)frag * 1024 + lane * 16) = pk.v;
        }
    } else {
        int bq = blk - 256;            // 0..511
        int b = bq >> 4, us = bq & 15, u0 = us * 64;
        if (zctx != nullptr && us == 0) {
            *(float4*)(zctx + b * 1024 + tid * 4) = make_float4(0.f, 0.f, 0.f, 0.f);
            if (b == 0 && tid < 32) zden[tid] = 0.f;
        }
        const float* q = query + b * 1024;
        #pragma unroll
        for (int i = 0; i < 4; ++i) qs[i * 256 + tid] = q[i * 256 + tid];
        __syncthreads();
        int ul = tid & 63, g = tid >> 6;       // 4 d-groups x 64 u
        float a = 0.f;
        const float* w2p = W2 + (size_t)(g * 256) * 1024 + u0 + ul;
        const float* qg = qs + g * 256;
        #pragma unroll 8
        for (int d = 0; d < 256; ++d)
            a += qg[d] * w2p[(size_t)d * 1024];
        part[g][ul] = a;
        __syncthreads();
        if (tid < 64) {
            float r = part[0][tid] + part[1][tid] + part[2][tid] + part[3][tid]
                    + b1[u0 + tid] + b2[u0 + tid];
            qp2[b * 1024 + u0 + tid] = r;
        }
    }
}

// ---------------- Kernel 2: fused score+exp+partial-context ----------
// Grid 1024 = 32 b * 32 row-tiles of 64. Block 512 (8 waves, 2/SIMD).
// r6 changes vs r5:
//  (1) K-quarter A double-buffer: A tile split into 4 k-quarters
//      (64 rows x 256 k bf16 = 32KB, 2 buffers). Quarter q+1 is staged
//      DURING quarter q's 8 MFMA iters (1 float4/thread on iters 0..3,
//      load at iter top, LDS write at iter bottom -> full-iter latency
//      cover). Only quarter 0's stage is serial. One lgkmcnt(0)+s_barrier
//      per quarter; B loads stay in flight across it.
//  (2) per-block k-rotation (rot = blockIdx.x & 7) inside each quarter:
//      concurrent CUs walk W1f at different offsets (de-camps L2 banks).
//      af and bfr rotate together; accumulation is k-order-independent.
// LDS: Aq[2][64 rows][32 chunks][16B] = 64KB + red 2KB = 66KB.
__global__ __launch_bounds__(512, 1) void k_score(
        const float* __restrict__ values, const __hip_bfloat16* __restrict__ W1f,
        const float* __restrict__ qp2, const float* __restrict__ V,
        float* __restrict__ escore, float* __restrict__ pctx,
        float* __restrict__ pden, float* __restrict__ ctxa) {
    extern __shared__ char smem[];
    float* red = (float*)(smem + 65536);        // [8 stripes][64 rows]

    const int tid = threadIdx.x;
    const int lane = tid & 63, w = tid >> 6;
    const int quad = lane >> 4, l15 = lane & 15;
    const int b = blockIdx.x >> 5, trow0 = (blockIdx.x & 31) << 6;
    const int rot = blockIdx.x & 7;

    const float* Ag = values + (size_t)(b * 2048 + trow0) * 1024;

    // stage mapping: step s (0..3): id = s*512+tid -> row = s*16 + (tid>>5),
    // chunk c = tid&31 (8 floats). row&15 == tid>>5 for all s, so the swizzle
    // position is per-thread constant. Global: 32 lanes x 32B = 1KB/row, coalesced.
    const int crow = tid >> 5, sc = tid & 31;
    const int pos_w = (sc & 16) | ((sc & 15) ^ crow);
    const float* sgbase = Ag + (size_t)crow * 1024 + sc * 8;
    char* wbase = smem + crow * 512 + pos_w * 16;   // + buf*32768 + s*8192

    // per-lane B fragment base: frag(ut = w*8 + ct, kg) at byte (ut*32+kg)*1024
    const char* Bbase = (const char*)W1f + (size_t)(w * 8) * 32768 + lane * 16;

    f32x4 acc[4][8];
    #pragma unroll
    for (int rt = 0; rt < 4; ++rt)
        #pragma unroll
        for (int ct = 0; ct < 8; ++ct) acc[rt][ct] = (f32x4){0.f, 0.f, 0.f, 0.f};

    bf16x8 bfr[2][8];

    // ---- prologue: stage quarter 0 into buf0; B prefetch for iter 0 ----
    #pragma unroll
    for (int s = 0; s < 4; ++s) {
        float4 v0 = *(const float4*)(sgbase + s * 16384);
        float4 v1 = *(const float4*)(sgbase + s * 16384 + 4);
        union { uint16_t h[8]; int4 v; } pk;
        pk.h[0]=f2b(v0.x); pk.h[1]=f2b(v0.y); pk.h[2]=f2b(v0.z); pk.h[3]=f2b(v0.w);
        pk.h[4]=f2b(v1.x); pk.h[5]=f2b(v1.y); pk.h[6]=f2b(v1.z); pk.h[7]=f2b(v1.w);
        *(int4*)(wbase + s * 8192) = pk.v;
    }
    #pragma unroll
    for (int ct = 0; ct < 8; ++ct)
        bfr[0][ct] = *(const bf16x8*)(Bbase + (size_t)(ct * 32 + rot) * 1024);
    asm volatile("s_waitcnt lgkmcnt(0)" ::: "memory");
    __builtin_amdgcn_s_barrier();
    __builtin_amdgcn_sched_barrier(0);

    // ---- k-loop: 4 quarters x 8 iters ----
    #pragma unroll
    for (int q = 0; q < 4; ++q) {
        const int abuf = q & 1;
        #pragma unroll
        for (int ksl = 0; ksl < 8; ++ksl) {
            const int it = q * 8 + ksl;
            const int curb = it & 1;
            const bool do_stage = (q < 3) && (ksl < 4);
            // stage loads for quarter q+1, step ksl (consumed at iter bottom)
            float4 sv0, sv1;
            if (do_stage) {
                const float* sp = sgbase + ksl * 16384 + (q + 1) * 256;
                sv0 = *(const float4*)sp;
                sv1 = *(const float4*)(sp + 4);
            }
            // af reads (single-buffered, rotated chunk of current quarter)
            const int lc = (ksl + rot) & 7;
            const int cbi = lc * 4 + quad;
            const int posr = (cbi & 16) | ((cbi & 15) ^ l15);
            bf16x8 af[4];
            #pragma unroll
            for (int rt = 0; rt < 4; ++rt)
                af[rt] = *(bf16x8*)(smem + abuf * 32768 + (rt * 16 + l15) * 512 + posr * 16);
            // next-iter B prefetch (rotated)
            if (it < 31) {
                const int nq = (ksl == 7) ? q + 1 : q;
                const int nlc = (ksl + 1 + rot) & 7;
                const int nkg = nq * 8 + nlc;
                #pragma unroll
                for (int ct = 0; ct < 8; ++ct)
                    bfr[curb ^ 1][ct] =
                        *(const bf16x8*)(Bbase + (size_t)(ct * 32 + nkg) * 1024);
            }
            __builtin_amdgcn_sched_barrier(0);
            // MFMA cluster 1: ct 0..3
            __builtin_amdgcn_s_setprio(1);
            #pragma unroll
            for (int ct = 0; ct < 4; ++ct)
                #pragma unroll
                for (int rt = 0; rt < 4; ++rt)
                    acc[rt][ct] = __builtin_amdgcn_mfma_f32_16x16x32_bf16(
                        af[rt], bfr[curb][ct], acc[rt][ct], 0, 0, 0);
            __builtin_amdgcn_s_setprio(0);
            __builtin_amdgcn_sched_barrier(0);
            // MFMA cluster 2: ct 4..7
            __builtin_amdgcn_s_setprio(1);
            #pragma unroll
            for (int ct = 4; ct < 8; ++ct)
                #pragma unroll
                for (int rt = 0; rt < 4; ++rt)
                    acc[rt][ct] = __builtin_amdgcn_mfma_f32_16x16x32_bf16(
                        af[rt], bfr[curb][ct], acc[rt][ct], 0, 0, 0);
            __builtin_amdgcn_s_setprio(0);
            __builtin_amdgcn_sched_barrier(0);
            // stage write (waits only on this iter's sv loads; B stays in flight)
            if (do_stage) {
                union { uint16_t h[8]; int4 v; } pk;
                pk.h[0]=f2b(sv0.x); pk.h[1]=f2b(sv0.y); pk.h[2]=f2b(sv0.z); pk.h[3]=f2b(sv0.w);
                pk.h[4]=f2b(sv1.x); pk.h[5]=f2b(sv1.y); pk.h[6]=f2b(sv1.z); pk.h[7]=f2b(sv1.w);
                *(int4*)(wbase + (abuf ^ 1) * 32768 + ksl * 8192) = pk.v;
            }
        }
        if (q < 3) {   // quarter boundary: A[next] must be visible to all
            asm volatile("s_waitcnt lgkmcnt(0)" ::: "memory");
            __builtin_amdgcn_s_barrier();
            __builtin_amdgcn_sched_barrier(0);
        }
    }

    // ---- epilogue: tanh(acc + qp2[u]) * V[u], per-lane row partials ----
    float srow[4][4];
    #pragma unroll
    for (int rt = 0; rt < 4; ++rt)
        #pragma unroll
        for (int r = 0; r < 4; ++r) srow[rt][r] = 0.f;
    #pragma unroll
    for (int ct = 0; ct < 8; ++ct) {
        int u = w * 128 + ct * 16 + l15;
        float qv = qp2[b * 1024 + u];
        float vv = V[u];
        #pragma unroll
        for (int rt = 0; rt < 4; ++rt)
            #pragma unroll
            for (int r = 0; r < 4; ++r) {
                float x = acc[rt][ct][r] + qv;
                float e = __expf(2.f * x);
                float t = 1.f - 2.f * __builtin_amdgcn_rcpf(1.f + e);
                srow[rt][r] += t * vv;
            }
    }

    // reduce u: over 16 lanes (l15), then over the 8 wave-stripes via LDS
    #pragma unroll
    for (int rt = 0; rt < 4; ++rt)
        #pragma unroll
        for (int r = 0; r < 4; ++r) {
            float s = srow[rt][r];
            s += __shfl_xor(s, 1, 64);
            s += __shfl_xor(s, 2, 64);
            s += __shfl_xor(s, 4, 64);
            s += __shfl_xor(s, 8, 64);
            srow[rt][r] = s;
        }
    if (l15 == 0) {
        #pragma unroll
        for (int rt = 0; rt < 4; ++rt)
            #pragma unroll
            for (int r = 0; r < 4; ++r)
                red[w * 64 + rt * 16 + quad * 4 + r] = srow[rt][r];
    }
    __syncthreads();

    // ---- fused: e = exp(score); partial denom; partial context ----
    float* wl = (float*)smem;    // alias A region (dead after the barrier)
    if (tid < 64) {
        float s = 0.f;
        #pragma unroll
        for (int k = 0; k < 8; ++k) s += red[k * 64 + tid];
        float e = __expf(s);
        escore[b * 2048 + trow0 + tid] = e;
        wl[tid] = e;
        float dsum = e;
        #pragma unroll
        for (int off = 32; off; off >>= 1) dsum += __shfl_xor(dsum, off, 64);
        if (tid == 0) {
            if (pctx != nullptr) pden[blockIdx.x] = dsum;
            else                 atomicAdd(&pden[b], dsum);
        }
    }
    __syncthreads();

    // weighted sum over this tile's 64 rows (L2/L3-warm re-read of values)
    {
        const float* Vg = values + (size_t)(b * 2048 + trow0) * 1024 + tid * 2;
        float ax = 0.f, ay = 0.f;
        #pragma unroll 8
        for (int t = 0; t < 64; ++t) {
            float wv = wl[t];
            float2 v = *(const float2*)(Vg + (size_t)t * 1024);
            ax += wv * v.x; ay += wv * v.y;
        }
        if (pctx != nullptr) {
            *(float2*)(pctx + (size_t)blockIdx.x * 1024 + tid * 2) = make_float2(ax, ay);
        } else {
            float* o = ctxa + b * 1024 + tid * 2;
            atomicAdd(o + 0, ax);
            atomicAdd(o + 1, ay);
        }
    }
}

// ---------------- Kernel 3: reduce partials, normalize ctx + attw ----
__global__ __launch_bounds__(256) void k_final(const float* __restrict__ pctx,
                                               const float* __restrict__ pden,
                                               const float* __restrict__ escore,
                                               float* __restrict__ out) {
    __shared__ float sinv;
    int b = blockIdx.x, tid = threadIdx.x;
    if (tid == 0) {
        float dsum = 0.f;
        if (pctx != nullptr) {
            #pragma unroll
            for (int t = 0; t < 32; ++t) dsum += pden[b * 32 + t];
        } else {
            dsum = pden[b];
        }
        sinv = 1.f / dsum;
    }
    __syncthreads();
    float inv = sinv;

    int d = tid * 4;
    if (pctx != nullptr) {
        float4 a = {0.f, 0.f, 0.f, 0.f};
        #pragma unroll 8
        for (int t = 0; t < 32; ++t) {
            float4 p = *(const float4*)(pctx + (size_t)(b * 32 + t) * 1024 + d);
            a.x += p.x; a.y += p.y; a.z += p.z; a.w += p.w;
        }
        a.x *= inv; a.y *= inv; a.z *= inv; a.w *= inv;
        *(float4*)(out + b * 1024 + d) = a;
    } else {
        float4 a = *(const float4*)(out + b * 1024 + d);
        a.x *= inv; a.y *= inv; a.z *= inv; a.w *= inv;
        *(float4*)(out + b * 1024 + d) = a;
    }

    // attention weights: e / denom (small mode: escore==out+32768, in-place)
    #pragma unroll
    for (int i = 0; i < 8; ++i) {
        int t = i * 256 + tid;
        out[32768 + b * 2048 + t] = escore[b * 2048 + t] * inv;
    }
}

extern "C" void kernel_launch(void* const* d_in, const int* in_sizes, int n_in,
                              void* d_out, int out_size, void* d_ws, size_t ws_size,
                              hipStream_t stream) {
    const float* query  = (const float*)d_in[0];
    const float* values = (const float*)d_in[1];
    const float* W1 = (const float*)d_in[2];
    const float* b1 = (const float*)d_in[3];
    const float* W2 = (const float*)d_in[4];
    const float* b2 = (const float*)d_in[5];
    const float* V  = (const float*)d_in[6];
    // d_in[7] = bv: constant pre-softmax -> cancels in softmax; unused.

    char* ws = (char*)d_ws;
    __hip_bfloat16* W1f = (__hip_bfloat16*)(ws + WS_W1F);
    float* qp2 = (float*)(ws + WS_QP2);
    float* out = (float*)d_out;

    const bool big = ws_size >= (size_t)WS_NEED;
    float* escore = big ? (float*)(ws + WS_ESC)  : out + 32768;
    float* pctx   = big ? (float*)(ws + WS_PCTX) : nullptr;
    float* pden   = big ? (float*)(ws + WS_PDEN) : (float*)(ws + WS_ESC);
    float* zctx   = big ? nullptr : out;
    float* zden   = big ? nullptr : pden;

    (void)hipFuncSetAttribute((const void*)k_score,
                              hipFuncAttributeMaxDynamicSharedMemorySize, 67584);

    k_prep<<<768, 256, 0, stream>>>(W1, query, W2, b1, b2, W1f, qp2, zctx, zden);
    k_score<<<1024, 512, 67584, stream>>>(values, W1f, qp2, V, escore, pctx, pden, out);
    k_final<<<32, 256, 0, stream>>>(pctx, pden, escore, out);
}

// Round 7
// 505.682 us; speedup vs baseline: 1.3184x; 1.0280x over previous
//
#include <hip/hip_runtime.h>
#include <hip/hip_bf16.h>
#include <stdint.h>

// Problem: B=32, T=2048, D=1024, U=1024, all fp32 in/out.
// out = [context 32*1024, attention_weights 32*2048]
//
// ws layout (big mode, needs WS_NEED bytes):
//   [0, 2MB)            W1f bf16 — W1 packed in MFMA B-fragment order
//   [2MB, +128KB)       qp2 fp32 [B][U] = query@W2 + b2 + b1
//   [+128KB, +256KB)    escore fp32 [B][T] = exp(score) (unnormalized)
//   [+256KB, +4MB)      pctx fp32 [1024 blocks][1024] partial contexts
//   [+4MB, +4KB)        pden fp32 [1024] partial softmax denominators
//
// small-ws fallback (fits the previously-verified 2.49MB footprint):
//   escore -> out attw region; pctx -> atomicAdd into out ctx (zeroed in init);
//   pden -> 32 floats at WS_ESC (atomicAdd, zeroed in init)
#define WS_W1F   0
#define WS_QP2   2097152
#define WS_ESC   (WS_QP2 + 131072)
#define WS_PCTX  (WS_ESC + 262144)
#define WS_PDEN  (WS_PCTX + 4194304)
#define WS_NEED  (WS_PDEN + 4096)

typedef __attribute__((ext_vector_type(8))) short bf16x8;
typedef __attribute__((ext_vector_type(4))) float f32x4;

__device__ inline uint16_t f2b(float f) {
    __hip_bfloat16 h = __float2bfloat16(f);
    return *reinterpret_cast<uint16_t*>(&h);
}

// ---------------- Kernel 0: init qp2 = b1+b2 (+ small-mode zeroing) --------
__global__ __launch_bounds__(256) void k_init(const float* __restrict__ b1,
                                              const float* __restrict__ b2,
                                              float* __restrict__ qp2,
                                              float* __restrict__ zctx,
                                              float* __restrict__ zden) {
    int b = blockIdx.x, tid = threadIdx.x;
    #pragma unroll
    for (int i = 0; i < 4; ++i) {
        int u = i * 256 + tid;
        qp2[b * 1024 + u] = b1[u] + b2[u];
    }
    if (zctx != nullptr) {
        *(float4*)(zctx + b * 1024 + tid * 4) = make_float4(0.f, 0.f, 0.f, 0.f);
        if (b == 0 && tid < 32) zden[tid] = 0.f;
    }
}

// ---------------- Kernel 1: prep = W1 repack + qp2 accumulate --------------
// blocks 0..255: repack 8 fragments each (2048 fragments of 1KB total)
// blocks 256..2303: qp2 partials: (b 32) x (uq 8: 128 u) x (dq 8: 128 d),
//   64 d-iters/thread, fp32 atomicAdd into qp2 (16 adds/address).
__global__ __launch_bounds__(256) void k_prep(const float* __restrict__ W1,
                                              const float* __restrict__ query,
                                              const float* __restrict__ W2,
                                              __hip_bfloat16* __restrict__ W1f,
                                              float* __restrict__ qp2) {
    __shared__ float qs[128];
    int blk = blockIdx.x, tid = threadIdx.x;
    if (blk < 256) {
        int lane = tid & 63, fi = tid >> 6;
        int l15 = lane & 15, quad = lane >> 4;
        #pragma unroll
        for (int p = 0; p < 2; ++p) {
            int frag = blk * 8 + p * 4 + fi;      // 0..2047
            int ut = frag >> 5, ks = frag & 31;
            union { uint16_t h[8]; int4 v; } pk;
            #pragma unroll
            for (int j = 0; j < 8; ++j) {
                float x = W1[(size_t)(ks * 32 + quad * 8 + j) * 1024 + ut * 16 + l15];
                pk.h[j] = f2b(x);
            }
            *(int4*)((char*)W1f + (size_t)frag * 1024 + lane * 16) = pk.v;
        }
    } else {
        int j = blk - 256;                 // 0..2047
        int b = j >> 6, rem = j & 63;
        int uq = rem >> 3, dq = rem & 7;
        if (tid < 128) qs[tid] = query[b * 1024 + dq * 128 + tid];
        __syncthreads();
        int ul = tid & 127, dh = tid >> 7;
        int u = uq * 128 + ul;
        const float* w2p = W2 + (size_t)(dq * 128 + dh * 64) * 1024 + u;
        const float* qg = qs + dh * 64;
        float a = 0.f;
        #pragma unroll 8
        for (int d = 0; d < 64; ++d)
            a += qg[d] * w2p[(size_t)d * 1024];
        atomicAdd(&qp2[b * 1024 + u], a);
    }
}

// ---------------- Kernel 2: fused score+exp+partial-context ----------
// Grid 1024 = 32 b * 32 row-tiles of 64. Block 512 (8 waves, 2/SIMD, 1 blk/CU).
// r7 changes vs r6:
//  (1) rot = (bid>>3)&7: blocks on the SAME XCD (bid%8) now get DIFFERENT
//      rotations (r6's bid&7 was XCD-correlated -> no-op within an L2).
//  (2) per-wave k-phase stagger: wave w consumes k-chunks in order
//      (ksl + w + rot)&7 within each quarter -> the 8 waves of a block hit
//      8 different 8KB B-regions at any instant (L2 de-camping). LDS/global
//      addresses are runtime-rotated; acc/MFMA indices stay STATIC.
//      fp32 k-accumulation order changes per wave: tolerance-level only.
// LDS: Aq[2][64 r][32 chunks][16B] = 64KB + red 2KB = 66KB.
__global__ __launch_bounds__(512, 1) void k_score(
        const float* __restrict__ values, const __hip_bfloat16* __restrict__ W1f,
        const float* __restrict__ qp2, const float* __restrict__ V,
        float* __restrict__ escore, float* __restrict__ pctx,
        float* __restrict__ pden, float* __restrict__ ctxa) {
    extern __shared__ char smem[];
    float* red = (float*)(smem + 65536);        // [8 stripes][64 rows]

    const int tid = threadIdx.x;
    const int lane = tid & 63, w = tid >> 6;
    const int quad = lane >> 4, l15 = lane & 15;
    const int b = blockIdx.x >> 5, trow0 = (blockIdx.x & 31) << 6;
    const int rot = (blockIdx.x >> 3) & 7;
    const int ph = (w + rot) & 7;               // per-wave k-phase

    const float* Ag = values + (size_t)(b * 2048 + trow0) * 1024;

    // stage mapping: step s (0..3): row = s*16 + (tid>>5), chunk c = tid&31.
    const int crow = tid >> 5, sc = tid & 31;
    const int pos_w = (sc & 16) | ((sc & 15) ^ crow);
    const float* sgbase = Ag + (size_t)crow * 1024 + sc * 8;
    char* wbase = smem + crow * 512 + pos_w * 16;   // + buf*32768 + s*8192

    // per-lane B fragment base: frag(ut = w*8 + ct, kg) at byte (ut*32+kg)*1024
    const char* Bbase = (const char*)W1f + (size_t)(w * 8) * 32768 + lane * 16;

    f32x4 acc[4][8];
    #pragma unroll
    for (int rt = 0; rt < 4; ++rt)
        #pragma unroll
        for (int ct = 0; ct < 8; ++ct) acc[rt][ct] = (f32x4){0.f, 0.f, 0.f, 0.f};

    bf16x8 bfr[2][8];

    // ---- prologue: stage quarter 0 into buf0; B prefetch for iter 0 ----
    #pragma unroll
    for (int s = 0; s < 4; ++s) {
        float4 v0 = *(const float4*)(sgbase + s * 16384);
        float4 v1 = *(const float4*)(sgbase + s * 16384 + 4);
        union { uint16_t h[8]; int4 v; } pk;
        pk.h[0]=f2b(v0.x); pk.h[1]=f2b(v0.y); pk.h[2]=f2b(v0.z); pk.h[3]=f2b(v0.w);
        pk.h[4]=f2b(v1.x); pk.h[5]=f2b(v1.y); pk.h[6]=f2b(v1.z); pk.h[7]=f2b(v1.w);
        *(int4*)(wbase + s * 8192) = pk.v;
    }
    {
        const int kg0 = ph;                    // q=0, ksl=0 rotated
        #pragma unroll
        for (int ct = 0; ct < 8; ++ct)
            bfr[0][ct] = *(const bf16x8*)(Bbase + (size_t)(ct * 32 + kg0) * 1024);
    }
    asm volatile("s_waitcnt lgkmcnt(0)" ::: "memory");
    __builtin_amdgcn_s_barrier();
    __builtin_amdgcn_sched_barrier(0);

    // ---- k-loop: 4 quarters x 8 iters ----
    #pragma unroll
    for (int q = 0; q < 4; ++q) {
        const int abuf = q & 1;
        #pragma unroll
        for (int ksl = 0; ksl < 8; ++ksl) {
            const int it = q * 8 + ksl;
            const int curb = it & 1;
            const bool do_stage = (q < 3) && (ksl < 4);
            // stage loads for quarter q+1, step ksl (consumed at iter bottom)
            float4 sv0, sv1;
            if (do_stage) {
                const float* sp = sgbase + ksl * 16384 + (q + 1) * 256;
                sv0 = *(const float4*)sp;
                sv1 = *(const float4*)(sp + 4);
            }
            // af reads: per-wave rotated chunk of current quarter
            const int lc = (ksl + ph) & 7;
            const int cbi = lc * 4 + quad;
            const int posr = (cbi & 16) | ((cbi & 15) ^ l15);
            bf16x8 af[4];
            #pragma unroll
            for (int rt = 0; rt < 4; ++rt)
                af[rt] = *(bf16x8*)(smem + abuf * 32768 + (rt * 16 + l15) * 512 + posr * 16);
            // next-iter B prefetch (rotated)
            if (it < 31) {
                const int nq = (ksl == 7) ? q + 1 : q;
                const int nksl = (ksl == 7) ? 0 : ksl + 1;
                const int nkg = nq * 8 + ((nksl + ph) & 7);
                #pragma unroll
                for (int ct = 0; ct < 8; ++ct)
                    bfr[curb ^ 1][ct] =
                        *(const bf16x8*)(Bbase + (size_t)(ct * 32 + nkg) * 1024);
            }
            __builtin_amdgcn_sched_barrier(0);
            // MFMA cluster 1: ct 0..3
            __builtin_amdgcn_s_setprio(1);
            #pragma unroll
            for (int ct = 0; ct < 4; ++ct)
                #pragma unroll
                for (int rt = 0; rt < 4; ++rt)
                    acc[rt][ct] = __builtin_amdgcn_mfma_f32_16x16x32_bf16(
                        af[rt], bfr[curb][ct], acc[rt][ct], 0, 0, 0);
            __builtin_amdgcn_s_setprio(0);
            __builtin_amdgcn_sched_barrier(0);
            // MFMA cluster 2: ct 4..7
            __builtin_amdgcn_s_setprio(1);
            #pragma unroll
            for (int ct = 4; ct < 8; ++ct)
                #pragma unroll
                for (int rt = 0; rt < 4; ++rt)
                    acc[rt][ct] = __builtin_amdgcn_mfma_f32_16x16x32_bf16(
                        af[rt], bfr[curb][ct], acc[rt][ct], 0, 0, 0);
            __builtin_amdgcn_s_setprio(0);
            __builtin_amdgcn_sched_barrier(0);
            // stage write (waits only on this iter's sv loads; B stays in flight)
            if (do_stage) {
                union { uint16_t h[8]; int4 v; } pk;
                pk.h[0]=f2b(sv0.x); pk.h[1]=f2b(sv0.y); pk.h[2]=f2b(sv0.z); pk.h[3]=f2b(sv0.w);
                pk.h[4]=f2b(sv1.x); pk.h[5]=f2b(sv1.y); pk.h[6]=f2b(sv1.z); pk.h[7]=f2b(sv1.w);
                *(int4*)(wbase + (abuf ^ 1) * 32768 + ksl * 8192) = pk.v;
            }
        }
        if (q < 3) {   // quarter boundary: A[next] must be visible to all
            asm volatile("s_waitcnt lgkmcnt(0)" ::: "memory");
            __builtin_amdgcn_s_barrier();
            __builtin_amdgcn_sched_barrier(0);
        }
    }

    // ---- epilogue: tanh(acc + qp2[u]) * V[u], per-lane row partials ----
    float srow[4][4];
    #pragma unroll
    for (int rt = 0; rt < 4; ++rt)
        #pragma unroll
        for (int r = 0; r < 4; ++r) srow[rt][r] = 0.f;
    #pragma unroll
    for (int ct = 0; ct < 8; ++ct) {
        int u = w * 128 + ct * 16 + l15;
        float qv = qp2[b * 1024 + u];
        float vv = V[u];
        #pragma unroll
        for (int rt = 0; rt < 4; ++rt)
            #pragma unroll
            for (int r = 0; r < 4; ++r) {
                float x = acc[rt][ct][r] + qv;
                float e = __expf(2.f * x);
                float t = 1.f - 2.f * __builtin_amdgcn_rcpf(1.f + e);
                srow[rt][r] += t * vv;
            }
    }

    // reduce u: over 16 lanes (l15), then over the 8 wave-stripes via LDS
    #pragma unroll
    for (int rt = 0; rt < 4; ++rt)
        #pragma unroll
        for (int r = 0; r < 4; ++r) {
            float s = srow[rt][r];
            s += __shfl_xor(s, 1, 64);
            s += __shfl_xor(s, 2, 64);
            s += __shfl_xor(s, 4, 64);
            s += __shfl_xor(s, 8, 64);
            srow[rt][r] = s;
        }
    if (l15 == 0) {
        #pragma unroll
        for (int rt = 0; rt < 4; ++rt)
            #pragma unroll
            for (int r = 0; r < 4; ++r)
                red[w * 64 + rt * 16 + quad * 4 + r] = srow[rt][r];
    }
    __syncthreads();

    // ---- fused: e = exp(score); partial denom; partial context ----
    float* wl = (float*)smem;    // alias A region (dead after the barrier)
    if (tid < 64) {
        float s = 0.f;
        #pragma unroll
        for (int k = 0; k < 8; ++k) s += red[k * 64 + tid];
        float e = __expf(s);
        escore[b * 2048 + trow0 + tid] = e;
        wl[tid] = e;
        float dsum = e;
        #pragma unroll
        for (int off = 32; off; off >>= 1) dsum += __shfl_xor(dsum, off, 64);
        if (tid == 0) {
            if (pctx != nullptr) pden[blockIdx.x] = dsum;
            else                 atomicAdd(&pden[b], dsum);
        }
    }
    __syncthreads();

    // weighted sum over this tile's 64 rows (L2/L3-warm re-read of values)
    {
        const float* Vg = values + (size_t)(b * 2048 + trow0) * 1024 + tid * 2;
        float ax = 0.f, ay = 0.f;
        #pragma unroll 8
        for (int t = 0; t < 64; ++t) {
            float wv = wl[t];
            float2 v = *(const float2*)(Vg + (size_t)t * 1024);
            ax += wv * v.x; ay += wv * v.y;
        }
        if (pctx != nullptr) {
            *(float2*)(pctx + (size_t)blockIdx.x * 1024 + tid * 2) = make_float2(ax, ay);
        } else {
            float* o = ctxa + b * 1024 + tid * 2;
            atomicAdd(o + 0, ax);
            atomicAdd(o + 1, ay);
        }
    }
}

// ---------------- Kernel 3: reduce partials, normalize ctx + attw ----
__global__ __launch_bounds__(256) void k_final(const float* __restrict__ pctx,
                                               const float* __restrict__ pden,
                                               const float* __restrict__ escore,
                                               float* __restrict__ out) {
    __shared__ float sinv;
    int b = blockIdx.x, tid = threadIdx.x;
    if (tid == 0) {
        float dsum = 0.f;
        if (pctx != nullptr) {
            #pragma unroll
            for (int t = 0; t < 32; ++t) dsum += pden[b * 32 + t];
        } else {
            dsum = pden[b];
        }
        sinv = 1.f / dsum;
    }
    __syncthreads();
    float inv = sinv;

    int d = tid * 4;
    if (pctx != nullptr) {
        float4 a = {0.f, 0.f, 0.f, 0.f};
        #pragma unroll 8
        for (int t = 0; t < 32; ++t) {
            float4 p = *(const float4*)(pctx + (size_t)(b * 32 + t) * 1024 + d);
            a.x += p.x; a.y += p.y; a.z += p.z; a.w += p.w;
        }
        a.x *= inv; a.y *= inv; a.z *= inv; a.w *= inv;
        *(float4*)(out + b * 1024 + d) = a;
    } else {
        float4 a = *(const float4*)(out + b * 1024 + d);
        a.x *= inv; a.y *= inv; a.z *= inv; a.w *= inv;
        *(float4*)(out + b * 1024 + d) = a;
    }

    // attention weights: e / denom (small mode: escore==out+32768, in-place)
    #pragma unroll
    for (int i = 0; i < 8; ++i) {
        int t = i * 256 + tid;
        out[32768 + b * 2048 + t] = escore[b * 2048 + t] * inv;
    }
}

extern "C" void kernel_launch(void* const* d_in, const int* in_sizes, int n_in,
                              void* d_out, int out_size, void* d_ws, size_t ws_size,
                              hipStream_t stream) {
    const float* query  = (const float*)d_in[0];
    const float* values = (const float*)d_in[1];
    const float* W1 = (const float*)d_in[2];
    const float* b1 = (const float*)d_in[3];
    const float* W2 = (const float*)d_in[4];
    const float* b2 = (const float*)d_in[5];
    const float* V  = (const float*)d_in[6];
    // d_in[7] = bv: constant pre-softmax -> cancels in softmax; unused.

    char* ws = (char*)d_ws;
    __hip_bfloat16* W1f = (__hip_bfloat16*)(ws + WS_W1F);
    float* qp2 = (float*)(ws + WS_QP2);
    float* out = (float*)d_out;

    const bool big = ws_size >= (size_t)WS_NEED;
    float* escore = big ? (float*)(ws + WS_ESC)  : out + 32768;
    float* pctx   = big ? (float*)(ws + WS_PCTX) : nullptr;
    float* pden   = big ? (float*)(ws + WS_PDEN) : (float*)(ws + WS_ESC);
    float* zctx   = big ? nullptr : out;
    float* zden   = big ? nullptr : pden;

    (void)hipFuncSetAttribute((const void*)k_score,
                              hipFuncAttributeMaxDynamicSharedMemorySize, 67584);

    k_init<<<32, 256, 0, stream>>>(b1, b2, qp2, zctx, zden);
    k_prep<<<2304, 256, 0, stream>>>(W1, query, W2, W1f, qp2);
    k_score<<<1024, 512, 67584, stream>>>(values, W1f, qp2, V, escore, pctx, pden, out);
    k_final<<<32, 256, 0, stream>>>(pctx, pden, escore, out);
}